// Round 5
// baseline (1050.733 us; speedup 1.0000x reference)
//
#include <hip/hip_runtime.h>
#include <hip/hip_bf16.h>
#include <cstdint>
#include <cstddef>

// ---------- constants ----------
// B=8, N=4096, C=768, NUM_HEADS=8, HEAD_DIM=96, BN = B*N = 32768

#define GLOAD_LDS16(g, l) \
  __builtin_amdgcn_global_load_lds((const __attribute__((address_space(1))) void*)(g), \
                                   (__attribute__((address_space(3))) void*)(l), 16, 0, 0)

typedef __attribute__((ext_vector_type(8))) short bf16x8;
typedef __attribute__((ext_vector_type(4))) float f32x4;

__device__ __forceinline__ ushort f2bf(float f) {
  union { float f; uint32_t u; } v; v.f = f;
  uint32_t u = v.u;
  uint32_t r = u + 0x7fffu + ((u >> 16) & 1u);   // RTNE
  return (ushort)(r >> 16);
}

// ---------- K0: f32 -> bf16 convert (vectorized) ----------
__global__ __launch_bounds__(256) void k_conv(const float* __restrict__ src,
                                              ushort* __restrict__ dst, int n4) {
  int i = blockIdx.x * blockDim.x + threadIdx.x;
  int stride = gridDim.x * blockDim.x;
  for (; i < n4; i += stride) {
    float4 v = ((const float4*)src)[i];
    ushort4 o;
    o.x = f2bf(v.x); o.y = f2bf(v.y); o.z = f2bf(v.z); o.w = f2bf(v.w);
    ((ushort4*)dst)[i] = o;
  }
}

// ---------- softplus(scale_p) -> 1/scale ----------
__global__ void k_softplus(const float* __restrict__ p, float* __restrict__ sinv) {
  int i = threadIdx.x + blockIdx.x * 256;
  if (i < 768) {
    float x = p[i];
    float s = (x > 20.f) ? x : log1pf(expf(x));
    sinv[i] = 1.0f / s;
  }
}

// ---------- GEMM (B^T layout): C[M][Nc] = A[M][K=768] * Bt[Nc][K]  (+bias) ----------
__global__ __launch_bounds__(256, 2) void gemm_bt(
    const ushort* __restrict__ A, const ushort* __restrict__ Bt,
    float* __restrict__ C, const float* __restrict__ bias, int Ncols) {
  constexpr int K = 768, BK = 64;
  __shared__ ushort lA[128 * BK];
  __shared__ ushort lB[128 * BK];
  const int tid  = threadIdx.x;
  const int lane = tid & 63;
  const int w    = tid >> 6;
  const int wr   = w >> 1, wc = w & 1;
  const int m0 = blockIdx.y * 128;
  const int n0 = blockIdx.x * 128;
  const int sr = lane >> 3;
  const int sc = (lane & 7) * 8;

  f32x4 acc[4][4] = {};

  for (int kt = 0; kt < K / BK; ++kt) {
    const int k0 = kt * BK;
    __syncthreads();
#pragma unroll
    for (int i = 0; i < 4; ++i) {
      const int ci = w * 4 + i;
      const int r  = ci * 8 + sr;
      GLOAD_LDS16(A  + (size_t)(m0 + r) * K + (k0 + sc), lA + ci * 512);
      GLOAD_LDS16(Bt + (size_t)(n0 + r) * K + (k0 + sc), lB + ci * 512);
    }
    __syncthreads();
#pragma unroll
    for (int kk = 0; kk < BK / 32; ++kk) {
      bf16x8 af[4], bfr[4];
#pragma unroll
      for (int m = 0; m < 4; ++m)
        af[m] = *(const bf16x8*)&lA[(wr * 64 + m * 16 + (lane & 15)) * BK + kk * 32 + (lane >> 4) * 8];
#pragma unroll
      for (int n = 0; n < 4; ++n)
        bfr[n] = *(const bf16x8*)&lB[(wc * 64 + n * 16 + (lane & 15)) * BK + kk * 32 + (lane >> 4) * 8];
#pragma unroll
      for (int m = 0; m < 4; ++m)
#pragma unroll
        for (int n = 0; n < 4; ++n)
          acc[m][n] = __builtin_amdgcn_mfma_f32_16x16x32_bf16(af[m], bfr[n], acc[m][n], 0, 0, 0);
    }
  }
#pragma unroll
  for (int n = 0; n < 4; ++n) {
    const int col = n0 + wc * 64 + n * 16 + (lane & 15);
    const float bv = bias ? bias[col] : 0.0f;
#pragma unroll
    for (int m = 0; m < 4; ++m) {
      const int row0 = m0 + wr * 64 + m * 16 + (lane >> 4) * 4;
#pragma unroll
      for (int j = 0; j < 4; ++j)
        C[(size_t)(row0 + j) * Ncols + col] = acc[m][n][j] + bv;
    }
  }
}

// ---------- K2: A_raw[row] = (q_row . w_g) * sf ; per-batch sumsq ----------
__global__ __launch_bounds__(256) void k_arow(const float* __restrict__ qk,
                                              const float* __restrict__ wg,
                                              float* __restrict__ A_raw,
                                              float* __restrict__ bsumsq) {
  __shared__ float lwg[768];
  __shared__ float lsq[4];
  const int tid = threadIdx.x, lane = tid & 63, w = tid >> 6;
  for (int i = tid; i < 768; i += 256) lwg[i] = wg[i];
  __syncthreads();
  const float sf = 0.10206207261596575f;  // 96^-0.5
  float wsq = 0.f;
  for (int r8 = 0; r8 < 8; ++r8) {
    const int row = blockIdx.x * 32 + w * 8 + r8;
    const float* qr = qk + (size_t)row * 1536;
    float d = 0.f;
#pragma unroll
    for (int i = 0; i < 12; ++i) d += qr[lane + 64 * i] * lwg[lane + 64 * i];
#pragma unroll
    for (int m = 32; m; m >>= 1) d += __shfl_xor(d, m);
    d *= sf;
    if (lane == 0) { A_raw[row] = d; wsq += d * d; }
  }
  if (lane == 0) lsq[w] = wsq;
  __syncthreads();
  if (tid == 0) atomicAdd(&bsumsq[blockIdx.x >> 7], lsq[0] + lsq[1] + lsq[2] + lsq[3]);
}

// ---------- K3: rnorm[b] = 1/max(sqrt(sumsq),1e-12) ----------
__global__ void k_rnorm(const float* __restrict__ bsumsq, float* __restrict__ rnorm) {
  int t = threadIdx.x;
  if (t < 8) rnorm[t] = 1.0f / fmaxf(sqrtf(bsumsq[t]), 1e-12f);
}

// ---------- K4 (rewritten): wave-per-row, register-only reductions ----------
// lane l owns channels c = 12l .. 12l+11; head h = l/8 (96 ch = 8 lanes)
// block = 4 waves = 32 rows (8 rows per wave, sequential)
__global__ __launch_bounds__(256) void k_gks(const float* __restrict__ qk,
                                             const float* __restrict__ pos,
                                             const float* __restrict__ A_raw,
                                             const float* __restrict__ rnorm,
                                             const float* __restrict__ sinv,
                                             float* __restrict__ G,
                                             float* __restrict__ ksum) {
  const int tid = threadIdx.x, lane = tid & 63, w = tid >> 6;
  const int b = blockIdx.x >> 7;
  const int c0 = lane * 12;
  float sv[12], ga[12] = {}, ka[12] = {};
#pragma unroll
  for (int v = 0; v < 3; ++v) {
    float4 s = *(const float4*)(sinv + c0 + v * 4);
    sv[v * 4] = s.x; sv[v * 4 + 1] = s.y; sv[v * 4 + 2] = s.z; sv[v * 4 + 3] = s.w;
  }
  const float rb = rnorm[b];
  for (int r = 0; r < 8; ++r) {
    const int row = blockIdx.x * 32 + w * 8 + r;
    const float* qr = qk + (size_t)row * 1536;
    const float* pr = pos + (size_t)(row & 4095) * 768;
    float q[12], kk[12], u[12];
    float s1 = 0.f, s2 = 0.f;
#pragma unroll
    for (int v = 0; v < 3; ++v) {
      float4 qv = *(const float4*)(qr + c0 + v * 4);
      float4 kv = *(const float4*)(qr + 768 + c0 + v * 4);
      float4 pv = *(const float4*)(pr + c0 + v * 4);
      q[v * 4] = qv.x; q[v * 4 + 1] = qv.y; q[v * 4 + 2] = qv.z; q[v * 4 + 3] = qv.w;
      kk[v * 4] = kv.x + pv.x; kk[v * 4 + 1] = kv.y + pv.y;
      kk[v * 4 + 2] = kv.z + pv.z; kk[v * 4 + 3] = kv.w + pv.w;
    }
#pragma unroll
    for (int j = 0; j < 12; ++j) {
      float t = (fmaxf(kk[j], 0.f) + 1e-6f) * sv[j];
      float uu = t * t * t;
      u[j] = uu;
      s1 += t * t; s2 += uu * uu;
    }
#pragma unroll
    for (int m = 32; m; m >>= 1) { s1 += __shfl_xor(s1, m); s2 += __shfl_xor(s2, m); }
    const float ratio = sqrtf(s1 / s2);
    const float a = A_raw[row] * rb;
#pragma unroll
    for (int j = 0; j < 12; ++j) { ka[j] += u[j] * ratio; ga[j] += a * q[j]; }
  }
#pragma unroll
  for (int j = 0; j < 12; ++j) {
    atomicAdd(&G[b * 768 + c0 + j], ga[j]);
    atomicAdd(&ksum[b * 768 + c0 + j], ka[j]);
  }
}

// ---------- K6 (rewritten): wave-per-row, no LDS atomics/barriers ----------
__global__ __launch_bounds__(256) void k_y(const float* __restrict__ qk,
                                           const float* __restrict__ G,
                                           const float* __restrict__ ksum,
                                           const float* __restrict__ sinv,
                                           ushort* __restrict__ y) {
  const int tid = threadIdx.x, lane = tid & 63, w = tid >> 6;
  const int row = blockIdx.x * 4 + w;
  const int b = row >> 12;
  const int c0 = lane * 12;
  const float* qr = qk + (size_t)row * 1536;
  float q[12], kk[12], u[12], ks[12], gg[12];
  float s1 = 0.f, s2 = 0.f;
#pragma unroll
  for (int v = 0; v < 3; ++v) {
    float4 qv = *(const float4*)(qr + c0 + v * 4);
    float4 kv = *(const float4*)(qr + 768 + c0 + v * 4);
    float4 sv = *(const float4*)(sinv + c0 + v * 4);
    float4 kv2 = *(const float4*)(ksum + b * 768 + c0 + v * 4);
    float4 gv = *(const float4*)(G + b * 768 + c0 + v * 4);
#pragma unroll
    for (int e = 0; e < 4; ++e) {
      const int j = v * 4 + e;
      const float qe = (&qv.x)[e];
      q[j] = qe; kk[j] = (&kv.x)[e];
      float t = (fmaxf(qe, 0.f) + 1e-6f) * (&sv.x)[e];
      float uu = t * t * t;
      u[j] = uu; s1 += t * t; s2 += uu * uu;
      ks[j] = (&kv2.x)[e]; gg[j] = (&gv.x)[e];
    }
  }
#pragma unroll
  for (int m = 32; m; m >>= 1) { s1 += __shfl_xor(s1, m); s2 += __shfl_xor(s2, m); }
  const float ratio = sqrtf(s1 / s2);
  float zp = 0.f;
#pragma unroll
  for (int j = 0; j < 12; ++j) zp += u[j] * ks[j];
  zp += __shfl_xor(zp, 1); zp += __shfl_xor(zp, 2); zp += __shfl_xor(zp, 4);  // 8-lane head sum
  const float z = 1.0f / (ratio * zp * (1.0f / 4096.0f) + 1e-6f);
  ushort o[12];
#pragma unroll
  for (int j = 0; j < 12; ++j) o[j] = f2bf(gg[j] * kk[j] * z);
  ushort* yp = y + (size_t)row * 768 + c0;
#pragma unroll
  for (int v = 0; v < 3; ++v)
    *(ushort4*)(yp + v * 4) = *(ushort4*)(o + v * 4);
}

// ---------- launcher ----------
extern "C" void kernel_launch(void* const* d_in, const int* in_sizes, int n_in,
                              void* d_out, int out_size, void* d_ws, size_t ws_size,
                              hipStream_t stream) {
  const float* x      = (const float*)d_in[0];
  const float* Wq     = (const float*)d_in[3];
  const float* Wkv    = (const float*)d_in[4];
  const float* Wproj  = (const float*)d_in[5];
  const float* bproj  = (const float*)d_in[6];
  const float* wg     = (const float*)d_in[7];
  const float* scalep = (const float*)d_in[8];
  const float* pos    = (const float*)d_in[9];

  char* ws = (char*)d_ws;
  float*  qk   = (float*)ws;                          // 32768*1536 f32
  ushort* xbf  = (ushort*)(ws + 201326592);           // 32768*768 bf16 (reused as y)
  ushort* ybf  = xbf;
  ushort* wqk  = (ushort*)(ws + 251658240);
  ushort* wpj  = (ushort*)(ws + 254017536);
  float*  sinv = (float*)(ws + 255197184);
  float*  araw = (float*)(ws + 255200256);
  float*  acc  = (float*)(ws + 255331328);
  float* bsumsq = acc;
  float* Gv     = acc + 8;
  float* ksum   = acc + 8 + 6144;
  float* rnorm  = acc + 8 + 12288;

  hipMemsetAsync(bsumsq, 0, (8 + 12288) * sizeof(float), stream);

  k_conv<<<4096, 256, 0, stream>>>(x, xbf, 25165824 / 4);
  k_conv<<<576, 256, 0, stream>>>(Wq, wqk, 589824 / 4);
  k_conv<<<576, 256, 0, stream>>>(Wkv, wqk + 589824, 589824 / 4);
  k_conv<<<576, 256, 0, stream>>>(Wproj, wpj, 589824 / 4);
  k_softplus<<<3, 256, 0, stream>>>(scalep, sinv);

  gemm_bt<<<dim3(12, 256), 256, 0, stream>>>(xbf, wqk, qk, nullptr, 1536);

  k_arow<<<1024, 256, 0, stream>>>(qk, wg, araw, bsumsq);
  k_rnorm<<<1, 64, 0, stream>>>(bsumsq, rnorm);
  k_gks<<<1024, 256, 0, stream>>>(qk, pos, araw, rnorm, sinv, Gv, ksum);
  k_y<<<8192, 256, 0, stream>>>(qk, Gv, ksum, sinv, ybf);

  gemm_bt<<<dim3(6, 256), 256, 0, stream>>>(ybf, wpj, (float*)d_out, bproj, 768);
}

// Round 6
// 486.424 us; speedup vs baseline: 2.1601x; 2.1601x over previous
//
#include <hip/hip_runtime.h>
#include <hip/hip_bf16.h>
#include <cstdint>
#include <cstddef>

// ---------- constants ----------
// B=8, N=4096, C=768, NUM_HEADS=8, HEAD_DIM=96, BN = B*N = 32768

#define GLOAD_LDS16(g, l) \
  __builtin_amdgcn_global_load_lds((const __attribute__((address_space(1))) void*)(g), \
                                   (__attribute__((address_space(3))) void*)(l), 16, 0, 0)

typedef __attribute__((ext_vector_type(8))) short bf16x8;
typedef __attribute__((ext_vector_type(4))) float f32x4;

__device__ __forceinline__ ushort f2bf(float f) {
  union { float f; uint32_t u; } v; v.f = f;
  uint32_t u = v.u;
  uint32_t r = u + 0x7fffu + ((u >> 16) & 1u);   // RTNE
  return (ushort)(r >> 16);
}

// ---------- K0: f32 -> bf16 convert (vectorized) ----------
__global__ __launch_bounds__(256) void k_conv(const float* __restrict__ src,
                                              ushort* __restrict__ dst, int n4) {
  int i = blockIdx.x * blockDim.x + threadIdx.x;
  int stride = gridDim.x * blockDim.x;
  for (; i < n4; i += stride) {
    float4 v = ((const float4*)src)[i];
    ushort4 o;
    o.x = f2bf(v.x); o.y = f2bf(v.y); o.z = f2bf(v.z); o.w = f2bf(v.w);
    ((ushort4*)dst)[i] = o;
  }
}

// ---------- softplus(scale_p) -> 1/scale ----------
__global__ void k_softplus(const float* __restrict__ p, float* __restrict__ sinv) {
  int i = threadIdx.x + blockIdx.x * 256;
  if (i < 768) {
    float x = p[i];
    float s = (x > 20.f) ? x : log1pf(expf(x));
    sinv[i] = 1.0f / s;
  }
}

// ---------- GEMM (B^T layout): C[M][Nc] = A[M][K=768] * Bt[Nc][K]  (+bias) ----------
__global__ __launch_bounds__(256, 2) void gemm_bt(
    const ushort* __restrict__ A, const ushort* __restrict__ Bt,
    float* __restrict__ C, const float* __restrict__ bias, int Ncols) {
  constexpr int K = 768, BK = 64;
  __shared__ ushort lA[128 * BK];
  __shared__ ushort lB[128 * BK];
  const int tid  = threadIdx.x;
  const int lane = tid & 63;
  const int w    = tid >> 6;
  const int wr   = w >> 1, wc = w & 1;
  const int m0 = blockIdx.y * 128;
  const int n0 = blockIdx.x * 128;
  const int sr = lane >> 3;
  const int sc = (lane & 7) * 8;

  f32x4 acc[4][4] = {};

  for (int kt = 0; kt < K / BK; ++kt) {
    const int k0 = kt * BK;
    __syncthreads();
#pragma unroll
    for (int i = 0; i < 4; ++i) {
      const int ci = w * 4 + i;
      const int r  = ci * 8 + sr;
      GLOAD_LDS16(A  + (size_t)(m0 + r) * K + (k0 + sc), lA + ci * 512);
      GLOAD_LDS16(Bt + (size_t)(n0 + r) * K + (k0 + sc), lB + ci * 512);
    }
    __syncthreads();
#pragma unroll
    for (int kk = 0; kk < BK / 32; ++kk) {
      bf16x8 af[4], bfr[4];
#pragma unroll
      for (int m = 0; m < 4; ++m)
        af[m] = *(const bf16x8*)&lA[(wr * 64 + m * 16 + (lane & 15)) * BK + kk * 32 + (lane >> 4) * 8];
#pragma unroll
      for (int n = 0; n < 4; ++n)
        bfr[n] = *(const bf16x8*)&lB[(wc * 64 + n * 16 + (lane & 15)) * BK + kk * 32 + (lane >> 4) * 8];
#pragma unroll
      for (int m = 0; m < 4; ++m)
#pragma unroll
        for (int n = 0; n < 4; ++n)
          acc[m][n] = __builtin_amdgcn_mfma_f32_16x16x32_bf16(af[m], bfr[n], acc[m][n], 0, 0, 0);
    }
  }
#pragma unroll
  for (int n = 0; n < 4; ++n) {
    const int col = n0 + wc * 64 + n * 16 + (lane & 15);
    const float bv = bias ? bias[col] : 0.0f;
#pragma unroll
    for (int m = 0; m < 4; ++m) {
      const int row0 = m0 + wr * 64 + m * 16 + (lane >> 4) * 4;
#pragma unroll
      for (int j = 0; j < 4; ++j)
        C[(size_t)(row0 + j) * Ncols + col] = acc[m][n][j] + bv;
    }
  }
}

// ---------- K2: A_raw[row] = (q_row . w_g) * sf ; per-batch sumsq ----------
__global__ __launch_bounds__(256) void k_arow(const float* __restrict__ qk,
                                              const float* __restrict__ wg,
                                              float* __restrict__ A_raw,
                                              float* __restrict__ bsumsq) {
  __shared__ float lwg[768];
  __shared__ float lsq[4];
  const int tid = threadIdx.x, lane = tid & 63, w = tid >> 6;
  for (int i = tid; i < 768; i += 256) lwg[i] = wg[i];
  __syncthreads();
  const float sf = 0.10206207261596575f;  // 96^-0.5
  float wsq = 0.f;
  for (int r8 = 0; r8 < 8; ++r8) {
    const int row = blockIdx.x * 32 + w * 8 + r8;
    const float* qr = qk + (size_t)row * 1536;
    float d = 0.f;
#pragma unroll
    for (int i = 0; i < 12; ++i) d += qr[lane + 64 * i] * lwg[lane + 64 * i];
#pragma unroll
    for (int m = 32; m; m >>= 1) d += __shfl_xor(d, m);
    d *= sf;
    if (lane == 0) { A_raw[row] = d; wsq += d * d; }
  }
  if (lane == 0) lsq[w] = wsq;
  __syncthreads();
  if (tid == 0) atomicAdd(&bsumsq[blockIdx.x >> 7], lsq[0] + lsq[1] + lsq[2] + lsq[3]);
}

// ---------- K3: rnorm[b] = 1/max(sqrt(sumsq),1e-12) ----------
__global__ void k_rnorm(const float* __restrict__ bsumsq, float* __restrict__ rnorm) {
  int t = threadIdx.x;
  if (t < 8) rnorm[t] = 1.0f / fmaxf(sqrtf(bsumsq[t]), 1e-12f);
}

// ---------- K4: wave-per-row register reductions; block partial -> scratch (NO atomics) ----------
// lane l owns channels c = 12l .. 12l+11; block = 4 waves = 32 rows
__global__ __launch_bounds__(256) void k_gks(const float* __restrict__ qk,
                                             const float* __restrict__ pos,
                                             const float* __restrict__ A_raw,
                                             const float* __restrict__ rnorm,
                                             const float* __restrict__ sinv,
                                             float* __restrict__ part) {
  __shared__ float pG[4][768];
  __shared__ float pK[4][768];
  const int tid = threadIdx.x, lane = tid & 63, w = tid >> 6;
  const int b = blockIdx.x >> 7;
  const int c0 = lane * 12;
  float sv[12], ga[12] = {}, ka[12] = {};
#pragma unroll
  for (int v = 0; v < 3; ++v) {
    float4 s = *(const float4*)(sinv + c0 + v * 4);
    sv[v * 4] = s.x; sv[v * 4 + 1] = s.y; sv[v * 4 + 2] = s.z; sv[v * 4 + 3] = s.w;
  }
  const float rb = rnorm[b];
  for (int r = 0; r < 8; ++r) {
    const int row = blockIdx.x * 32 + w * 8 + r;
    const float* qr = qk + (size_t)row * 1536;
    const float* pr = pos + (size_t)(row & 4095) * 768;
    float q[12], kk[12], u[12];
    float s1 = 0.f, s2 = 0.f;
#pragma unroll
    for (int v = 0; v < 3; ++v) {
      float4 qv = *(const float4*)(qr + c0 + v * 4);
      float4 kv = *(const float4*)(qr + 768 + c0 + v * 4);
      float4 pv = *(const float4*)(pr + c0 + v * 4);
      q[v * 4] = qv.x; q[v * 4 + 1] = qv.y; q[v * 4 + 2] = qv.z; q[v * 4 + 3] = qv.w;
      kk[v * 4] = kv.x + pv.x; kk[v * 4 + 1] = kv.y + pv.y;
      kk[v * 4 + 2] = kv.z + pv.z; kk[v * 4 + 3] = kv.w + pv.w;
    }
#pragma unroll
    for (int j = 0; j < 12; ++j) {
      float t = (fmaxf(kk[j], 0.f) + 1e-6f) * sv[j];
      float uu = t * t * t;
      u[j] = uu;
      s1 += t * t; s2 += uu * uu;
    }
#pragma unroll
    for (int m = 32; m; m >>= 1) { s1 += __shfl_xor(s1, m); s2 += __shfl_xor(s2, m); }
    const float ratio = sqrtf(s1 / s2);
    const float a = A_raw[row] * rb;
#pragma unroll
    for (int j = 0; j < 12; ++j) { ka[j] += u[j] * ratio; ga[j] += a * q[j]; }
  }
#pragma unroll
  for (int j = 0; j < 12; ++j) { pG[w][c0 + j] = ga[j]; pK[w][c0 + j] = ka[j]; }
  __syncthreads();
  float* outp = part + (size_t)blockIdx.x * 1536;
  for (int i = tid; i < 768; i += 256) {
    outp[i]       = pG[0][i] + pG[1][i] + pG[2][i] + pG[3][i];
    outp[768 + i] = pK[0][i] + pK[1][i] + pK[2][i] + pK[3][i];
  }
}

// ---------- K5: reduce 128 block-partials per batch -> G, ksum ----------
__global__ __launch_bounds__(256) void k_gred(const float* __restrict__ part,
                                              float* __restrict__ G,
                                              float* __restrict__ ksum) {
  const int i = blockIdx.x * 256 + threadIdx.x;   // 0..1535
  const int b = blockIdx.y;
  const float* p = part + (size_t)b * 128 * 1536 + i;
  float s = 0.f;
#pragma unroll 8
  for (int blk = 0; blk < 128; ++blk) s += p[(size_t)blk * 1536];
  if (i < 768) G[b * 768 + i] = s;
  else         ksum[b * 768 + i - 768] = s;
}

// ---------- K6: wave-per-row, no LDS atomics/barriers ----------
__global__ __launch_bounds__(256) void k_y(const float* __restrict__ qk,
                                           const float* __restrict__ G,
                                           const float* __restrict__ ksum,
                                           const float* __restrict__ sinv,
                                           ushort* __restrict__ y) {
  const int tid = threadIdx.x, lane = tid & 63, w = tid >> 6;
  const int row = blockIdx.x * 4 + w;
  const int b = row >> 12;
  const int c0 = lane * 12;
  const float* qr = qk + (size_t)row * 1536;
  float q[12], kk[12], u[12], ks[12], gg[12];
  float s1 = 0.f, s2 = 0.f;
#pragma unroll
  for (int v = 0; v < 3; ++v) {
    float4 qv = *(const float4*)(qr + c0 + v * 4);
    float4 kv = *(const float4*)(qr + 768 + c0 + v * 4);
    float4 sv = *(const float4*)(sinv + c0 + v * 4);
    float4 kv2 = *(const float4*)(ksum + b * 768 + c0 + v * 4);
    float4 gv = *(const float4*)(G + b * 768 + c0 + v * 4);
#pragma unroll
    for (int e = 0; e < 4; ++e) {
      const int j = v * 4 + e;
      const float qe = (&qv.x)[e];
      q[j] = qe; kk[j] = (&kv.x)[e];
      float t = (fmaxf(qe, 0.f) + 1e-6f) * (&sv.x)[e];
      float uu = t * t * t;
      u[j] = uu; s1 += t * t; s2 += uu * uu;
      ks[j] = (&kv2.x)[e]; gg[j] = (&gv.x)[e];
    }
  }
#pragma unroll
  for (int m = 32; m; m >>= 1) { s1 += __shfl_xor(s1, m); s2 += __shfl_xor(s2, m); }
  const float ratio = sqrtf(s1 / s2);
  float zp = 0.f;
#pragma unroll
  for (int j = 0; j < 12; ++j) zp += u[j] * ks[j];
  zp += __shfl_xor(zp, 1); zp += __shfl_xor(zp, 2); zp += __shfl_xor(zp, 4);  // 8-lane head sum
  const float z = 1.0f / (ratio * zp * (1.0f / 4096.0f) + 1e-6f);
  ushort o[12];
#pragma unroll
  for (int j = 0; j < 12; ++j) o[j] = f2bf(gg[j] * kk[j] * z);
  ushort* yp = y + (size_t)row * 768 + c0;
#pragma unroll
  for (int v = 0; v < 3; ++v)
    *(ushort4*)(yp + v * 4) = *(ushort4*)(o + v * 4);
}

// ---------- launcher ----------
extern "C" void kernel_launch(void* const* d_in, const int* in_sizes, int n_in,
                              void* d_out, int out_size, void* d_ws, size_t ws_size,
                              hipStream_t stream) {
  const float* x      = (const float*)d_in[0];
  const float* Wq     = (const float*)d_in[3];
  const float* Wkv    = (const float*)d_in[4];
  const float* Wproj  = (const float*)d_in[5];
  const float* bproj  = (const float*)d_in[6];
  const float* wg     = (const float*)d_in[7];
  const float* scalep = (const float*)d_in[8];
  const float* pos    = (const float*)d_in[9];

  char* ws = (char*)d_ws;
  float*  qk   = (float*)ws;                          // 32768*1536 f32 = 192 MiB
  ushort* xbf  = (ushort*)(ws + 201326592);           // 48 MiB; reused: part (6.3MB) then y
  ushort* ybf  = xbf;
  float*  part = (float*)(ws + 201326592);            // aliases xbf: gemm1 done before k_gks,
                                                      // k_y overwrites after k_gred consumed it
  ushort* wqk  = (ushort*)(ws + 251658240);
  ushort* wpj  = (ushort*)(ws + 254017536);
  float*  sinv = (float*)(ws + 255197184);
  float*  araw = (float*)(ws + 255200256);
  float*  acc  = (float*)(ws + 255331328);
  float* bsumsq = acc;
  float* Gv     = acc + 8;
  float* ksum   = acc + 8 + 6144;
  float* rnorm  = acc + 8 + 12288;

  hipMemsetAsync(bsumsq, 0, 8 * sizeof(float), stream);

  k_conv<<<4096, 256, 0, stream>>>(x, xbf, 25165824 / 4);
  k_conv<<<576, 256, 0, stream>>>(Wq, wqk, 589824 / 4);
  k_conv<<<576, 256, 0, stream>>>(Wkv, wqk + 589824, 589824 / 4);
  k_conv<<<576, 256, 0, stream>>>(Wproj, wpj, 589824 / 4);
  k_softplus<<<3, 256, 0, stream>>>(scalep, sinv);

  gemm_bt<<<dim3(12, 256), 256, 0, stream>>>(xbf, wqk, qk, nullptr, 1536);

  k_arow<<<1024, 256, 0, stream>>>(qk, wg, araw, bsumsq);
  k_rnorm<<<1, 64, 0, stream>>>(bsumsq, rnorm);
  k_gks<<<1024, 256, 0, stream>>>(qk, pos, araw, rnorm, sinv, part);
  k_gred<<<dim3(6, 8), 256, 0, stream>>>(part, Gv, ksum);
  k_y<<<8192, 256, 0, stream>>>(qk, Gv, ksum, sinv, ybf);

  gemm_bt<<<dim3(6, 256), 256, 0, stream>>>(ybf, wpj, (float*)d_out, bproj, 768);
}

// Round 7
// 423.616 us; speedup vs baseline: 2.4804x; 1.1483x over previous
//
#include <hip/hip_runtime.h>
#include <hip/hip_bf16.h>
#include <cstdint>
#include <cstddef>

// B=8, N=4096, C=768, NUM_HEADS=8, HEAD_DIM=96, BN = 32768

#define GLOAD_LDS16(g, l) \
  __builtin_amdgcn_global_load_lds((const __attribute__((address_space(1))) void*)(g), \
                                   (__attribute__((address_space(3))) void*)(l), 16, 0, 0)

typedef __attribute__((ext_vector_type(8))) short bf16x8;
typedef __attribute__((ext_vector_type(4))) float f32x4;

__device__ __forceinline__ ushort f2bf(float f) {
  union { float f; uint32_t u; } v; v.f = f;
  uint32_t r = v.u + 0x7fffu + ((v.u >> 16) & 1u);   // RTNE
  return (ushort)(r >> 16);
}
__device__ __forceinline__ float bf2f(ushort u) {
  union { uint32_t x; float f; } v; v.x = (uint32_t)u << 16; return v.f;
}

// ---------- K0: f32 -> bf16 convert ----------
__global__ __launch_bounds__(256) void k_conv(const float* __restrict__ src,
                                              ushort* __restrict__ dst, int n4) {
  int i = blockIdx.x * blockDim.x + threadIdx.x;
  int stride = gridDim.x * blockDim.x;
  for (; i < n4; i += stride) {
    float4 v = ((const float4*)src)[i];
    ushort4 o;
    o.x = f2bf(v.x); o.y = f2bf(v.y); o.z = f2bf(v.z); o.w = f2bf(v.w);
    ((ushort4*)dst)[i] = o;
  }
}

// ---------- softplus(scale_p) -> 1/scale ----------
__global__ void k_softplus(const float* __restrict__ p, float* __restrict__ sinv) {
  int i = threadIdx.x + blockIdx.x * 256;
  if (i < 768) {
    float x = p[i];
    float s = (x > 20.f) ? x : log1pf(expf(x));
    sinv[i] = 1.0f / s;
  }
}

// ---------- GEMM: C[M][Nc] = A[M][768] * Bt[Nc][768]; BF16OUT selects output ----------
template <bool BF16OUT>
__global__ __launch_bounds__(256, 2) void gemm_bt(
    const ushort* __restrict__ A, const ushort* __restrict__ Bt,
    void* __restrict__ Cv, const float* __restrict__ bias, int Ncols) {
  constexpr int K = 768, BK = 64;
  __shared__ ushort lA[128 * BK];
  __shared__ ushort lB[128 * BK];
  const int tid  = threadIdx.x;
  const int lane = tid & 63;
  const int w    = tid >> 6;
  const int wr   = w >> 1, wc = w & 1;
  const int m0 = blockIdx.y * 128;
  const int n0 = blockIdx.x * 128;
  const int sr = lane >> 3;
  const int sc = (lane & 7) * 8;

  f32x4 acc[4][4] = {};

  for (int kt = 0; kt < K / BK; ++kt) {
    const int k0 = kt * BK;
    __syncthreads();
#pragma unroll
    for (int i = 0; i < 4; ++i) {
      const int ci = w * 4 + i;
      const int r  = ci * 8 + sr;
      GLOAD_LDS16(A  + (size_t)(m0 + r) * K + (k0 + sc), lA + ci * 512);
      GLOAD_LDS16(Bt + (size_t)(n0 + r) * K + (k0 + sc), lB + ci * 512);
    }
    __syncthreads();
#pragma unroll
    for (int kk = 0; kk < BK / 32; ++kk) {
      bf16x8 af[4], bfr[4];
#pragma unroll
      for (int m = 0; m < 4; ++m)
        af[m] = *(const bf16x8*)&lA[(wr * 64 + m * 16 + (lane & 15)) * BK + kk * 32 + (lane >> 4) * 8];
#pragma unroll
      for (int n = 0; n < 4; ++n)
        bfr[n] = *(const bf16x8*)&lB[(wc * 64 + n * 16 + (lane & 15)) * BK + kk * 32 + (lane >> 4) * 8];
#pragma unroll
      for (int m = 0; m < 4; ++m)
#pragma unroll
        for (int n = 0; n < 4; ++n)
          acc[m][n] = __builtin_amdgcn_mfma_f32_16x16x32_bf16(af[m], bfr[n], acc[m][n], 0, 0, 0);
    }
  }
#pragma unroll
  for (int n = 0; n < 4; ++n) {
    const int col = n0 + wc * 64 + n * 16 + (lane & 15);
    const float bv = (!BF16OUT && bias) ? bias[col] : 0.0f;
#pragma unroll
    for (int m = 0; m < 4; ++m) {
      const int row0 = m0 + wr * 64 + m * 16 + (lane >> 4) * 4;
#pragma unroll
      for (int j = 0; j < 4; ++j) {
        if (BF16OUT)
          ((ushort*)Cv)[(size_t)(row0 + j) * Ncols + col] = f2bf(acc[m][n][j]);
        else
          ((float*)Cv)[(size_t)(row0 + j) * Ncols + col] = acc[m][n][j] + bv;
      }
    }
  }
}

// ---------- K4: fused A-dot + G/ksum partials; wave-per-row, register-only, NO atomics ----------
// lane l owns channels c = 12l..12l+11; block = 4 waves x 8 rows = 32 rows
__global__ __launch_bounds__(256) void k_gks(const ushort* __restrict__ qk,
                                             const float* __restrict__ pos,
                                             const float* __restrict__ wg,
                                             const float* __restrict__ sinv,
                                             float* __restrict__ part,
                                             float* __restrict__ partW) {
  __shared__ float pG[4][768];
  __shared__ float pK[4][768];
  __shared__ float lsq[4];
  const int tid = threadIdx.x, lane = tid & 63, w = tid >> 6;
  const int c0 = lane * 12;
  float sv[12], wv[12], ga[12] = {}, ka[12] = {};
#pragma unroll
  for (int v = 0; v < 3; ++v) {
    float4 s = *(const float4*)(sinv + c0 + v * 4);
    float4 g = *(const float4*)(wg + c0 + v * 4);
#pragma unroll
    for (int e = 0; e < 4; ++e) { sv[v * 4 + e] = (&s.x)[e]; wv[v * 4 + e] = (&g.x)[e]; }
  }
  float wsq = 0.f;
  for (int r = 0; r < 8; ++r) {
    const int row = blockIdx.x * 32 + w * 8 + r;
    const ushort* qr = qk + (size_t)row * 1536;
    const float* pr = pos + (size_t)(row & 4095) * 768;
    float q[12], kk[12], u[12];
    float d = 0.f, s1 = 0.f, s2 = 0.f;
#pragma unroll
    for (int v = 0; v < 3; ++v) {
      ushort4 qv = *(const ushort4*)(qr + c0 + v * 4);
      ushort4 kv = *(const ushort4*)(qr + 768 + c0 + v * 4);
      float4 pv = *(const float4*)(pr + c0 + v * 4);
#pragma unroll
      for (int e = 0; e < 4; ++e) {
        const int j = v * 4 + e;
        q[j] = bf2f((&qv.x)[e]);
        kk[j] = bf2f((&kv.x)[e]) + (&pv.x)[e];
      }
    }
#pragma unroll
    for (int j = 0; j < 12; ++j) {
      d += q[j] * wv[j];
      float t = (fmaxf(kk[j], 0.f) + 1e-6f) * sv[j];
      float uu = t * t * t;
      u[j] = uu;
      s1 += t * t; s2 += uu * uu;
    }
#pragma unroll
    for (int m = 32; m; m >>= 1) {
      d += __shfl_xor(d, m); s1 += __shfl_xor(s1, m); s2 += __shfl_xor(s2, m);
    }
    const float ratio = sqrtf(s1 / s2);
    wsq += d * d;
#pragma unroll
    for (int j = 0; j < 12; ++j) { ka[j] += u[j] * ratio; ga[j] += d * q[j]; }
  }
#pragma unroll
  for (int j = 0; j < 12; ++j) { pG[w][c0 + j] = ga[j]; pK[w][c0 + j] = ka[j]; }
  if (lane == 0) lsq[w] = wsq;
  __syncthreads();
  float* outp = part + (size_t)blockIdx.x * 1536;
  for (int i = tid; i < 768; i += 256) {
    outp[i]       = pG[0][i] + pG[1][i] + pG[2][i] + pG[3][i];
    outp[768 + i] = pK[0][i] + pK[1][i] + pK[2][i] + pK[3][i];
  }
  if (tid == 0) partW[blockIdx.x] = lsq[0] + lsq[1] + lsq[2] + lsq[3];
}

// ---------- K3: rnorm[b] from 128 wsq partials ----------
// A_hat = sf*d / max(sf*||d||, 1e-12)  ->  rnorm = sf / max(sf*sqrt(wsq), 1e-12)
__global__ __launch_bounds__(256) void k_rnorm(const float* __restrict__ partW,
                                               float* __restrict__ rnorm) {
  const int tid = threadIdx.x;
  const int b = tid >> 5, j = tid & 31;
  float s = 0.f;
#pragma unroll
  for (int v = 0; v < 4; ++v) s += partW[b * 128 + j * 4 + v];
#pragma unroll
  for (int m = 16; m; m >>= 1) s += __shfl_xor(s, m);
  if (j == 0) {
    const float sf = 0.10206207261596575f;  // 96^-0.5
    rnorm[b] = sf / fmaxf(sf * sqrtf(s), 1e-12f);
  }
}

// ---------- K5: reduce 128 block-partials -> G (scaled by rnorm), ksum ----------
__global__ __launch_bounds__(256) void k_gred(const float* __restrict__ part,
                                              const float* __restrict__ rnorm,
                                              float* __restrict__ G,
                                              float* __restrict__ ksum) {
  const int i = blockIdx.x * 256 + threadIdx.x;   // 0..1535
  const int b = blockIdx.y;
  const float* p = part + (size_t)b * 128 * 1536 + i;
  float s = 0.f;
#pragma unroll 8
  for (int blk = 0; blk < 128; ++blk) s += p[(size_t)blk * 1536];
  if (i < 768) G[b * 768 + i] = s * rnorm[b];
  else         ksum[b * 768 + i - 768] = s;
}

// ---------- K6: wave-per-row -> y (bf16) ----------
__global__ __launch_bounds__(256) void k_y(const ushort* __restrict__ qk,
                                           const float* __restrict__ G,
                                           const float* __restrict__ ksum,
                                           const float* __restrict__ sinv,
                                           ushort* __restrict__ y) {
  const int tid = threadIdx.x, lane = tid & 63, w = tid >> 6;
  const int row = blockIdx.x * 4 + w;
  const int b = row >> 12;
  const int c0 = lane * 12;
  const ushort* qr = qk + (size_t)row * 1536;
  float kk[12], u[12], ks[12], gg[12];
  float s1 = 0.f, s2 = 0.f;
#pragma unroll
  for (int v = 0; v < 3; ++v) {
    ushort4 qv = *(const ushort4*)(qr + c0 + v * 4);
    ushort4 kv = *(const ushort4*)(qr + 768 + c0 + v * 4);
    float4 sv = *(const float4*)(sinv + c0 + v * 4);
    float4 kv2 = *(const float4*)(ksum + b * 768 + c0 + v * 4);
    float4 gv = *(const float4*)(G + b * 768 + c0 + v * 4);
#pragma unroll
    for (int e = 0; e < 4; ++e) {
      const int j = v * 4 + e;
      kk[j] = bf2f((&kv.x)[e]);
      float t = (fmaxf(bf2f((&qv.x)[e]), 0.f) + 1e-6f) * (&sv.x)[e];
      float uu = t * t * t;
      u[j] = uu; s1 += t * t; s2 += uu * uu;
      ks[j] = (&kv2.x)[e]; gg[j] = (&gv.x)[e];
    }
  }
#pragma unroll
  for (int m = 32; m; m >>= 1) { s1 += __shfl_xor(s1, m); s2 += __shfl_xor(s2, m); }
  const float ratio = sqrtf(s1 / s2);
  float zp = 0.f;
#pragma unroll
  for (int j = 0; j < 12; ++j) zp += u[j] * ks[j];
  zp += __shfl_xor(zp, 1); zp += __shfl_xor(zp, 2); zp += __shfl_xor(zp, 4);  // head (8 lanes)
  const float z = 1.0f / (ratio * zp * (1.0f / 4096.0f) + 1e-6f);
  ushort o[12];
#pragma unroll
  for (int j = 0; j < 12; ++j) o[j] = f2bf(gg[j] * kk[j] * z);
  ushort* yp = y + (size_t)row * 768 + c0;
#pragma unroll
  for (int v = 0; v < 3; ++v)
    *(ushort4*)(yp + v * 4) = *(ushort4*)(o + v * 4);
}

// ---------- launcher ----------
extern "C" void kernel_launch(void* const* d_in, const int* in_sizes, int n_in,
                              void* d_out, int out_size, void* d_ws, size_t ws_size,
                              hipStream_t stream) {
  const float* x      = (const float*)d_in[0];
  const float* Wq     = (const float*)d_in[3];
  const float* Wkv    = (const float*)d_in[4];
  const float* Wproj  = (const float*)d_in[5];
  const float* bproj  = (const float*)d_in[6];
  const float* wg     = (const float*)d_in[7];
  const float* scalep = (const float*)d_in[8];
  const float* pos    = (const float*)d_in[9];

  char* ws = (char*)d_ws;
  ushort* qk   = (ushort*)ws;                         // 32768*1536 bf16 = 96 MiB
  ushort* xbf  = (ushort*)(ws + 100663296);           // 48 MiB; reused: part, then y
  ushort* ybf  = xbf;
  float*  part = (float*)(ws + 100663296);            // 6.3 MiB, aliases xbf (dead by then)
  ushort* wqk  = (ushort*)(ws + 150994944);           // 2.25 MiB
  ushort* wpj  = (ushort*)(ws + 153354240);           // 1.125 MiB
  float*  sinv = (float*)(ws + 154533888);            // 768 f32
  float*  partW = (float*)(ws + 154536960);           // 1024 f32
  float*  accb  = (float*)(ws + 154541056);
  float* Gv     = accb;                               // 6144
  float* ksum   = accb + 6144;                        // 6144
  float* rnorm  = accb + 12288;                       // 8

  k_conv<<<4096, 256, 0, stream>>>(x, xbf, 25165824 / 4);
  k_conv<<<576, 256, 0, stream>>>(Wq, wqk, 589824 / 4);
  k_conv<<<576, 256, 0, stream>>>(Wkv, wqk + 589824, 589824 / 4);
  k_conv<<<576, 256, 0, stream>>>(Wproj, wpj, 589824 / 4);
  k_softplus<<<3, 256, 0, stream>>>(scalep, sinv);

  gemm_bt<true><<<dim3(12, 256), 256, 0, stream>>>(xbf, wqk, qk, nullptr, 1536);

  k_gks<<<1024, 256, 0, stream>>>(qk, pos, wg, sinv, part, partW);
  k_rnorm<<<1, 256, 0, stream>>>(partW, rnorm);
  k_gred<<<dim3(6, 8), 256, 0, stream>>>(part, rnorm, Gv, ksum);
  k_y<<<8192, 256, 0, stream>>>(qk, Gv, ksum, sinv, ybf);

  gemm_bt<false><<<dim3(6, 256), 256, 0, stream>>>(ybf, wpj, d_out, bproj, 768);
}